// Round 9
// baseline (369.388 us; speedup 1.0000x reference)
//
#include <hip/hip_runtime.h>
#include <math.h>

#define HIDDEN 1024
#define SEQ    2048
#define NHEAD  16
#define HDIM   64
#define ROWS   (2 * SEQ)

typedef float  floatx4  __attribute__((ext_vector_type(4)));
typedef float  floatx16 __attribute__((ext_vector_type(16)));
typedef __bf16 bf16x8   __attribute__((ext_vector_type(8)));
typedef __bf16 bf16x4   __attribute__((ext_vector_type(4)));

#define AS1(p) ((const __attribute__((address_space(1))) void*)(p))
#define AS3(p) ((__attribute__((address_space(3))) void*)(p))

// swizzled byte-chunk offset (in elements): 16B chunks XOR'd by row&7 (attn)
#define SWZ(row, chunk) ((((chunk) ^ ((row) & 7)) * 8))

// ---------------------------------------------------------------------------
// Prep launch: 6 weight converts (fp32 [K][N] -> FRAGMENT-MAJOR bf16 BtF) +
// LayerNorm1 + out=emb copy, all in ONE kernel.
// BtF layout: blk = (n>>5)*(K>>4) + (k>>4); elem at blk*512 + lane*8 + (k&7),
// lane = ((k>>3)&1)*32 + (n&31). A wave B-fragment load is then one
// fully-coalesced 1KB read at blk*512 + lane*16B.
// ---------------------------------------------------------------------------
__global__ __launch_bounds__(256) void prep_all(const float* __restrict__ Wq,
                                                const float* __restrict__ Wk,
                                                const float* __restrict__ Wv,
                                                const float* __restrict__ Wo,
                                                const float* __restrict__ W1,
                                                const float* __restrict__ W2,
                                                __bf16* __restrict__ BtQKV,
                                                __bf16* __restrict__ BtO,
                                                __bf16* __restrict__ Bt1,
                                                __bf16* __restrict__ Bt2,
                                                const float* __restrict__ emb,
                                                const float* __restrict__ g1,
                                                const float* __restrict__ be1,
                                                __bf16* __restrict__ h,
                                                float* __restrict__ xout) {
    int id = blockIdx.x;
    int tid = threadIdx.x;
    if (id >= 12288) {
        // ---- LayerNorm1 row + out = emb copy ----
        int row = id - 12288;
        size_t i = (size_t)row * HIDDEN + tid * 4;
        float4 v = *(const float4*)(emb + i);
        *(float4*)(xout + i) = v;          // pre-init residual stream
        float s  = v.x + v.y + v.z + v.w;
        float s2 = v.x * v.x + v.y * v.y + v.z * v.z + v.w * v.w;
#pragma unroll
        for (int off = 1; off < 64; off <<= 1) {
            s  += __shfl_xor(s, off, 64);
            s2 += __shfl_xor(s2, off, 64);
        }
        __shared__ float red[8];
        int wid = tid >> 6;
        if ((tid & 63) == 0) { red[wid] = s; red[wid + 4] = s2; }
        __syncthreads();
        s  = red[0] + red[1] + red[2] + red[3];
        s2 = red[4] + red[5] + red[6] + red[7];
        float mu  = s * (1.0f / HIDDEN);
        float var = fmaxf(s2 * (1.0f / HIDDEN) - mu * mu, 0.0f);
        float inv = rsqrtf(var + 1e-5f);
        float4 gv = *(const float4*)(g1 + tid * 4);
        float4 bv = *(const float4*)(be1 + tid * 4);
        bf16x4 o;
        o[0] = (__bf16)((v.x - mu) * inv * gv.x + bv.x);
        o[1] = (__bf16)((v.y - mu) * inv * gv.y + bv.y);
        o[2] = (__bf16)((v.z - mu) * inv * gv.z + bv.z);
        o[3] = (__bf16)((v.w - mu) * inv * gv.w + bv.w);
        *(bf16x4*)(h + i) = o;
        return;
    }
    // ---- weight convert tile (32x32) ----
    __shared__ float t[32][33];
    const float* in; __bf16* out; int K, N, nt, kt;
    if (id < 4096) {
        int job = id >> 10, tt = id & 1023;
        nt = tt & 31; kt = tt >> 5; K = 1024; N = 1024;
        if (job == 0)      { in = Wq; out = BtQKV; }
        else if (job == 1) { in = Wk; out = BtQKV + 1024 * 1024; }
        else if (job == 2) { in = Wv; out = BtQKV + 2 * 1024 * 1024; }
        else               { in = Wo; out = BtO; }
    } else if (id < 8192) {
        int tt = id - 4096;
        nt = tt & 127; kt = tt >> 7; K = 1024; N = 4096; in = W1; out = Bt1;
    } else {
        int tt = id - 8192;
        nt = tt & 31; kt = tt >> 5; K = 4096; N = 1024; in = W2; out = Bt2;
    }
    int n0 = nt * 32, k0 = kt * 32;
    int r  = tid >> 3;             // n within tile
    int c4 = (tid & 7) * 4;        // k run of 4
    float4 v = *(const float4*)(in + (size_t)(k0 + r) * N + n0 + c4);
    t[r][c4 + 0] = v.x; t[r][c4 + 1] = v.y; t[r][c4 + 2] = v.z; t[r][c4 + 3] = v.w;
    __syncthreads();
    bf16x4 o;
    o[0] = (__bf16)t[c4 + 0][r];
    o[1] = (__bf16)t[c4 + 1][r];
    o[2] = (__bf16)t[c4 + 2][r];
    o[3] = (__bf16)t[c4 + 3][r];
    int n = n0 + r, k = k0 + c4;
    size_t blk = (size_t)(n >> 5) * (K >> 4) + (k >> 4);
    int ln = ((k >> 3) & 1) * 32 + (n & 31);
    *(bf16x4*)(out + blk * 512 + ln * 8 + (k & 7)) = o;
}

// ---------------------------------------------------------------------------
// x1 = out (already emb + Wo-partials via atomics); h2 = LN2(x1);
// out = x1 + b2 (pre-adds W2's bias for the atomic W2 epilogue).
// ---------------------------------------------------------------------------
__global__ __launch_bounds__(256) void red_ln(const float* __restrict__ b2,
                                              const float* __restrict__ g,
                                              const float* __restrict__ beta,
                                              float* __restrict__ out,
                                              __bf16* __restrict__ h2) {
    int row = blockIdx.x;
    int tid = threadIdx.x;
    size_t i = (size_t)row * HIDDEN + tid * 4;
    float4 v = *(const float4*)(out + i);       // x1
    float s  = v.x + v.y + v.z + v.w;
    float s2 = v.x * v.x + v.y * v.y + v.z * v.z + v.w * v.w;
#pragma unroll
    for (int off = 1; off < 64; off <<= 1) {
        s  += __shfl_xor(s, off, 64);
        s2 += __shfl_xor(s2, off, 64);
    }
    __shared__ float red[8];
    int wid = tid >> 6;
    if ((tid & 63) == 0) { red[wid] = s; red[wid + 4] = s2; }
    __syncthreads();
    s  = red[0] + red[1] + red[2] + red[3];
    s2 = red[4] + red[5] + red[6] + red[7];
    float mu  = s * (1.0f / HIDDEN);
    float var = fmaxf(s2 * (1.0f / HIDDEN) - mu * mu, 0.0f);
    float inv = rsqrtf(var + 1e-5f);
    float4 gv = *(const float4*)(g + tid * 4);
    float4 bv = *(const float4*)(beta + tid * 4);
    bf16x4 o;
    o[0] = (__bf16)((v.x - mu) * inv * gv.x + bv.x);
    o[1] = (__bf16)((v.y - mu) * inv * gv.y + bv.y);
    o[2] = (__bf16)((v.z - mu) * inv * gv.z + bv.z);
    o[3] = (__bf16)((v.w - mu) * inv * gv.w + bv.w);
    *(bf16x4*)(h2 + i) = o;
    float4 bb = *(const float4*)(b2 + tid * 4);
    v.x += bb.x; v.y += bb.y; v.z += bb.z; v.w += bb.w;
    *(float4*)(out + i) = v;
}

// ---------------------------------------------------------------------------
// Shared MFMA core, 32x32x16. A via LDS (XOR-swizzled, double-buffered
// global_load_lds); B DIRECT global->VGPR from fragment-major BtF with
// one-iteration register prefetch (each load = one coalesced 1KB read).
// ---------------------------------------------------------------------------
__device__ __forceinline__ void mfma_core128(const __bf16* __restrict__ A,
                                             const __bf16* __restrict__ BtF,
                                             int Kstride, int kbase, int Klen,
                                             int m0, int n0, int tid,
                                             floatx16 (&acc)[2][2]) {
    __shared__ __bf16 As[2 * 128 * 32];
    const int BUF = 128 * 32;
    int lane = tid & 63;
    int wave = tid >> 6;
    int wr = wave >> 1, wc = wave & 1;

    int sr = lane >> 2;                                // row within 16
    int sk = 8 * ((lane & 3) ^ ((sr >> 1) & 3));       // swizzled global chunk
    const __bf16* ga0 = A + (size_t)(m0 + wave * 16 + sr) * Kstride + kbase + sk;
    const __bf16* ga1 = ga0 + (size_t)64 * Kstride;
    __bf16* la0 = &As[wave * 512];
    __bf16* la1 = &As[2048 + wave * 512];

    int fm = lane & 31;
    int gswz = (lane >> 1) & 3;
    int slot0 = ((lane >> 5) + 0) ^ gswz;
    int slot1 = ((lane >> 5) + 2) ^ gswz;

    const __bf16* bb = BtF + ((size_t)((n0 >> 5) + wc * 2) * (Kstride >> 4)) * 512
                     + (size_t)lane * 8;
    const size_t jstr = (size_t)(Kstride >> 4) * 512;
    int ci0 = kbase >> 4;

    // preload: A tile 0 -> buf0; B regs for iter 0
    __builtin_amdgcn_global_load_lds(AS1(ga0), AS3(la0), 16, 0, 0);
    __builtin_amdgcn_global_load_lds(AS1(ga1), AS3(la1), 16, 0, 0);
    bf16x8 bcur[2][2], bnxt[2][2];
#pragma unroll
    for (int j = 0; j < 2; j++)
#pragma unroll
        for (int t = 0; t < 2; t++)
            bcur[j][t] = *(const bf16x8*)(bb + j * jstr + (size_t)(ci0 + t) * 512);

    int buf = 0;
    for (int k0 = 0; k0 < Klen; k0 += 32, buf ^= 1) {
        __syncthreads();   // buf's staging landed; prev reads of buf^1 done
        if (k0 + 32 < Klen) {
            int nb = (buf ^ 1) * BUF;
            __builtin_amdgcn_global_load_lds(AS1(ga0 + k0 + 32), AS3(la0 + nb), 16, 0, 0);
            __builtin_amdgcn_global_load_lds(AS1(ga1 + k0 + 32), AS3(la1 + nb), 16, 0, 0);
            int ci = ci0 + ((k0 + 32) >> 4);
#pragma unroll
            for (int j = 0; j < 2; j++)
#pragma unroll
                for (int t = 0; t < 2; t++)
                    bnxt[j][t] = *(const bf16x8*)(bb + j * jstr + (size_t)(ci + t) * 512);
        }
        const __bf16* Ab = As + buf * BUF;
        bf16x8 af[2][2];
#pragma unroll
        for (int i = 0; i < 2; i++) {
            const __bf16* rp = Ab + (size_t)(wr * 64 + i * 32 + fm) * 32;
            af[i][0] = *(const bf16x8*)(rp + slot0 * 8);
            af[i][1] = *(const bf16x8*)(rp + slot1 * 8);
        }
#pragma unroll
        for (int t = 0; t < 2; t++)
#pragma unroll
            for (int i = 0; i < 2; i++)
#pragma unroll
                for (int j = 0; j < 2; j++)
                    acc[i][j] = __builtin_amdgcn_mfma_f32_32x32x16_bf16(
                        af[i][t], bcur[j][t], acc[i][j], 0, 0, 0);
#pragma unroll
        for (int j = 0; j < 2; j++)
#pragma unroll
            for (int t = 0; t < 2; t++)
                bcur[j][t] = bnxt[j][t];
    }
}

// ---------------------------------------------------------------------------
// Full-K GEMM with epilogue (W1). Grid: x = M-tiles, y = N-tiles.
// ---------------------------------------------------------------------------
template <typename OutT, bool BIAS, bool RELU>
__global__ __launch_bounds__(256) void mgemm(const __bf16* __restrict__ A,
                                             const __bf16* __restrict__ BtF,
                                             const float* __restrict__ bias,
                                             OutT* __restrict__ C,
                                             int N, int Kstride, int Klen) {
    int tid = threadIdx.x;
    int lane = tid & 63;
    int wave = tid >> 6;
    int m0 = blockIdx.x * 128, n0 = blockIdx.y * 128;
    int wr = wave >> 1, wc = wave & 1;
    floatx16 acc[2][2] = {};
    mfma_core128(A, BtF, Kstride, 0, Klen, m0, n0, tid, acc);

#pragma unroll
    for (int i = 0; i < 2; i++) {
#pragma unroll
        for (int j = 0; j < 2; j++) {
            int col  = n0 + wc * 64 + j * 32 + (lane & 31);
            int rowb = m0 + wr * 64 + i * 32 + 4 * (lane >> 5);
#pragma unroll
            for (int reg = 0; reg < 16; reg++) {
                int row = rowb + (reg & 3) + 8 * (reg >> 2);
                float v = acc[i][j][reg];
                if (BIAS) v += bias[col];
                if (RELU) v = fmaxf(v, 0.0f);
                C[(size_t)row * N + col] = (OutT)v;
            }
        }
    }
}

// ---------------------------------------------------------------------------
// QKV GEMM: q,k parts to qkv[4096][3072]; v-part written only as transposed
// Vt[bh][d][T] (vtrans-free).
// ---------------------------------------------------------------------------
__global__ __launch_bounds__(256) void mgemm_qkv(const __bf16* __restrict__ A,
                                                 const __bf16* __restrict__ BtF,
                                                 __bf16* __restrict__ C,
                                                 __bf16* __restrict__ Vt) {
    const int N = 3072;
    int tid = threadIdx.x;
    int lane = tid & 63;
    int wave = tid >> 6;
    int m0 = blockIdx.x * 128, n0 = blockIdx.y * 128;
    int wr = wave >> 1, wc = wave & 1;
    floatx16 acc[2][2] = {};
    mfma_core128(A, BtF, 1024, 0, 1024, m0, n0, tid, acc);

#pragma unroll
    for (int i = 0; i < 2; i++) {
#pragma unroll
        for (int j = 0; j < 2; j++) {
            int col  = n0 + wc * 64 + j * 32 + (lane & 31);
            int rowb = m0 + wr * 64 + i * 32 + 4 * (lane >> 5);
            if (col < 2048) {
#pragma unroll
                for (int reg = 0; reg < 16; reg++) {
                    int row = rowb + (reg & 3) + 8 * (reg >> 2);
                    C[(size_t)row * N + col] = (__bf16)acc[i][j][reg];
                }
            } else {
                int vcol = col - 2048;
                int hh = vcol >> 6, dd = vcol & 63;
#pragma unroll
                for (int rq = 0; rq < 4; rq++) {
                    int row0 = rowb + 8 * rq;
                    int bb = row0 >> 11;
                    int tt = row0 & 2047;
                    bf16x4 pack;
                    pack[0] = (__bf16)acc[i][j][4 * rq + 0];
                    pack[1] = (__bf16)acc[i][j][4 * rq + 1];
                    pack[2] = (__bf16)acc[i][j][4 * rq + 2];
                    pack[3] = (__bf16)acc[i][j][4 * rq + 3];
                    *(bf16x4*)&Vt[(((size_t)bb * 16 + hh) * 64 + dd) * SEQ + tt] = pack;
                }
            }
        }
    }
}

// ---------------------------------------------------------------------------
// Split-K GEMM with fp32 ATOMIC epilogue: z-chunk partials accumulate
// directly into out (pre-initialized by prep_all / red_ln).
// ---------------------------------------------------------------------------
__global__ __launch_bounds__(256) void mgemm_ska(const __bf16* __restrict__ A,
                                                 const __bf16* __restrict__ BtF,
                                                 float* __restrict__ out,
                                                 int N, int Kstride, int Klen) {
    int z = blockIdx.z;
    int tid = threadIdx.x;
    int lane = tid & 63;
    int wave = tid >> 6;
    int m0 = blockIdx.x * 128, n0 = blockIdx.y * 128;
    int wr = wave >> 1, wc = wave & 1;
    floatx16 acc[2][2] = {};
    mfma_core128(A, BtF, Kstride, z * Klen, Klen, m0, n0, tid, acc);

#pragma unroll
    for (int i = 0; i < 2; i++) {
#pragma unroll
        for (int j = 0; j < 2; j++) {
            int col  = n0 + wc * 64 + j * 32 + (lane & 31);
            int rowb = m0 + wr * 64 + i * 32 + 4 * (lane >> 5);
#pragma unroll
            for (int reg = 0; reg < 16; reg++) {
                int row = rowb + (reg & 3) + 8 * (reg >> 2);
                unsafeAtomicAdd(&out[(size_t)row * N + col], acc[i][j][reg]);
            }
        }
    }
}

// ---------------------------------------------------------------------------
// MFMA flash attention (verified R8): no-max softmax, exp2, ones-MFMA l,
// K/V register prefetch.
// ---------------------------------------------------------------------------
__global__ __launch_bounds__(256) void attn_mfma(const __bf16* __restrict__ qkv,
                                                 const __bf16* __restrict__ Vt,
                                                 __bf16* __restrict__ ctx) {
    __shared__ __bf16 Ks[64 * 64];
    __shared__ __bf16 Vs[64 * 64];
    __shared__ __bf16 Ps[4][16 * 64];
    const int QKVW = 3 * HIDDEN;

    int bh = blockIdx.x;
    int qt = gridDim.y - 1 - blockIdx.y;
    int b = bh >> 4, h = bh & 15;
    int tid = threadIdx.x;
    int lane = tid & 63;
    int w = tid >> 6;
    int m = lane & 15;
    int g = lane >> 4;

    const float QSC = 1.44269504f / 8.0f;
    bf16x8 qf[2];
    {
        const __bf16* Qp = qkv + (size_t)(b * SEQ + qt * 64 + w * 16 + m) * QKVW
                         + h * HDIM + g * 8;
        qf[0] = *(const bf16x8*)(Qp);
        qf[1] = *(const bf16x8*)(Qp + 32);
#pragma unroll
        for (int t = 0; t < 2; t++)
#pragma unroll
            for (int i = 0; i < 8; i++)
                qf[t][i] = (__bf16)((float)qf[t][i] * QSC);
    }

    bf16x8 onesf;
#pragma unroll
    for (int i = 0; i < 8; i++) onesf[i] = (__bf16)1.0f;

    floatx4 oacc[4] = {};
    floatx4 lacc = {};

    int srow = tid >> 2;
    int sc0  = (tid & 3) * 2;
    const __bf16* Kg = qkv + (size_t)(b * SEQ) * QKVW + HIDDEN + h * HDIM;
    const __bf16* Vg = Vt + (size_t)bh * HDIM * SEQ;

    bf16x8 pk0, pk1, pv0, pv1;
    {
        const __bf16* kp = Kg + (size_t)srow * QKVW + sc0 * 8;
        pk0 = *(const bf16x8*)kp;
        pk1 = *(const bf16x8*)(kp + 8);
        const __bf16* vp = Vg + (size_t)srow * SEQ + sc0 * 8;
        pv0 = *(const bf16x8*)vp;
        pv1 = *(const bf16x8*)(vp + 8);
    }

    for (int kt = 0; kt <= qt; kt++) {
        __syncthreads();
        *(bf16x8*)&Ks[srow * 64 + SWZ(srow, sc0)]     = pk0;
        *(bf16x8*)&Ks[srow * 64 + SWZ(srow, sc0 + 1)] = pk1;
        *(bf16x8*)&Vs[srow * 64 + SWZ(srow, sc0)]     = pv0;
        *(bf16x8*)&Vs[srow * 64 + SWZ(srow, sc0 + 1)] = pv1;
        __syncthreads();

        if (kt < qt) {
            const __bf16* kp = Kg + (size_t)((kt + 1) * 64 + srow) * QKVW + sc0 * 8;
            pk0 = *(const bf16x8*)kp;
            pk1 = *(const bf16x8*)(kp + 8);
            const __bf16* vp = Vg + (size_t)srow * SEQ + (kt + 1) * 64 + sc0 * 8;
            pv0 = *(const bf16x8*)vp;
            pv1 = *(const bf16x8*)(vp + 8);
        }

        floatx4 sacc[4] = {};
#pragma unroll
        for (int j = 0; j < 4; j++) {
#pragma unroll
            for (int t = 0; t < 2; t++) {
                int kr = 16 * j + m;
                bf16x8 kf = *(const bf16x8*)&Ks[kr * 64 + SWZ(kr, g + 4 * t)];
                sacc[j] = __builtin_amdgcn_mfma_f32_16x16x32_bf16(
                    qf[t], kf, sacc[j], 0, 0, 0);
            }
        }

        if (kt == qt) {
            int qlocal = w * 16 + 4 * g;
#pragma unroll
            for (int j = 0; j < 4; j++)
#pragma unroll
                for (int r = 0; r < 4; r++)
                    if (16 * j + m > qlocal + r) sacc[j][r] = -INFINITY;
        }

        __bf16* Pw = &Ps[w][0];
#pragma unroll
        for (int j = 0; j < 4; j++)
#pragma unroll
            for (int r = 0; r < 4; r++) {
                float p = exp2f(sacc[j][r]);
                int row = 4 * g + r;
                int key = 16 * j + m;
                Pw[row * 64 + SWZ(row, key >> 3) + (key & 7)] = (__bf16)p;
            }

#pragma unroll
        for (int t = 0; t < 2; t++) {
            bf16x8 pf = *(const bf16x8*)&Pw[m * 64 + SWZ(m, g + 4 * t)];
            lacc = __builtin_amdgcn_mfma_f32_16x16x32_bf16(pf, onesf, lacc, 0, 0, 0);
#pragma unroll
            for (int jd = 0; jd < 4; jd++) {
                int vr = 16 * jd + m;
                bf16x8 vf = *(const bf16x8*)&Vs[vr * 64 + SWZ(vr, g + 4 * t)];
                oacc[jd] = __builtin_amdgcn_mfma_f32_16x16x32_bf16(
                    pf, vf, oacc[jd], 0, 0, 0);
            }
        }
    }

#pragma unroll
    for (int r = 0; r < 4; r++) {
        float invl = 1.0f / lacc[r];
        int row = qt * 64 + w * 16 + 4 * g + r;
        __bf16* cp = ctx + (size_t)(b * SEQ + row) * HIDDEN + h * HDIM;
#pragma unroll
        for (int jd = 0; jd < 4; jd++)
            cp[16 * jd + m] = (__bf16)(oacc[jd][r] * invl);
    }
}

// ---------------------------------------------------------------------------
extern "C" void kernel_launch(void* const* d_in, const int* in_sizes, int n_in,
                              void* d_out, int out_size, void* d_ws, size_t ws_size,
                              hipStream_t stream) {
    (void)in_sizes; (void)n_in; (void)out_size; (void)ws_size;
    const float* emb = (const float*)d_in[0];
    const float* Wq  = (const float*)d_in[1];
    const float* Wk  = (const float*)d_in[2];
    const float* Wv  = (const float*)d_in[3];
    const float* Wo  = (const float*)d_in[4];
    const float* W1  = (const float*)d_in[5];
    const float* b1  = (const float*)d_in[6];
    const float* W2  = (const float*)d_in[7];
    const float* b2  = (const float*)d_in[8];
    const float* g1  = (const float*)d_in[9];
    const float* be1 = (const float*)d_in[10];
    const float* g2  = (const float*)d_in[11];
    const float* be2 = (const float*)d_in[12];
    float* out = (float*)d_out;

    // ws layout (bf16 elems; ME = 1M elems = 2MB). Total 36 ME = 72 MB.
    //   [0,4)   h (LN1) -> ctx (attn out)
    //   [4,16)  qkv (q,k used; v cols unwritten) -> ff1 overlays after red_ln
    //   [0,16)  ff1
    //   [16,20) h2
    //   [20,23) BtQKV  [23,24) BtO  [24,28) Bt1  [28,32) Bt2  [32,36) Vt
    __bf16* wsb = (__bf16*)d_ws;
    const size_t ME = 1024 * 1024;
    __bf16* h     = wsb;
    __bf16* qkv   = wsb + 4 * ME;
    __bf16* ctx   = wsb;
    __bf16* ff1   = wsb;
    __bf16* h2    = wsb + 16 * ME;
    __bf16* BtQKV = wsb + 20 * ME;
    __bf16* BtO   = wsb + 23 * ME;
    __bf16* Bt1   = wsb + 24 * ME;
    __bf16* Bt2   = wsb + 28 * ME;
    __bf16* Vt    = wsb + 32 * ME;

    // weight converts (fragment-major) + LN1 + out=emb, one launch
    prep_all<<<16384, 256, 0, stream>>>(Wq, Wk, Wv, Wo, W1, W2,
                                        BtQKV, BtO, Bt1, Bt2,
                                        emb, g1, be1, h, out);

    // QKV GEMM; v-part emitted directly as Vt (transposed)
    mgemm_qkv<<<dim3(32, 24), 256, 0, stream>>>(h, BtQKV, qkv, Vt);

    attn_mfma<<<dim3(32, 32), 256, 0, stream>>>(qkv, Vt, ctx);

    // Wo split-K x2, fp32 atomics into out (= emb + ctx@Wo after this)
    mgemm_ska<<<dim3(32, 8, 2), 256, 0, stream>>>(
        ctx, BtO, out, 1024, 1024, 512);

    // h2 = LN2(x1); out = x1 + b2
    red_ln<<<ROWS, 256, 0, stream>>>(b2, g2, be2, out, h2);

    // ff1 = relu(h2 @ W1 + b1)
    mgemm<__bf16, true, true><<<dim3(32, 32), 256, 0, stream>>>(
        h2, Bt1, b1, ff1, 4096, 1024, 1024);

    // W2 split-K x4, fp32 atomics into out (final result)
    mgemm_ska<<<dim3(32, 8, 4), 256, 0, stream>>>(
        ff1, Bt2, out, 1024, 4096, 1024);
}

// Round 10
// 322.645 us; speedup vs baseline: 1.1449x; 1.1449x over previous
//
#include <hip/hip_runtime.h>
#include <math.h>

#define HIDDEN 1024
#define SEQ    2048
#define NHEAD  16
#define HDIM   64
#define ROWS   (2 * SEQ)

typedef float  floatx4  __attribute__((ext_vector_type(4)));
typedef float  floatx16 __attribute__((ext_vector_type(16)));
typedef __bf16 bf16x8   __attribute__((ext_vector_type(8)));
typedef __bf16 bf16x4   __attribute__((ext_vector_type(4)));

#define AS1(p) ((const __attribute__((address_space(1))) void*)(p))
#define AS3(p) ((__attribute__((address_space(3))) void*)(p))

// swizzled byte-chunk offset (in elements): 16B chunks XOR'd by row&7 (attn)
#define SWZ(row, chunk) ((((chunk) ^ ((row) & 7)) * 8))

// ---------------------------------------------------------------------------
// Prep launch: 6 weight converts (fp32 [K][N] -> FRAGMENT-MAJOR bf16 BtF) +
// LayerNorm1, one kernel.
// BtF layout: blk = (n>>5)*(K>>4) + (k>>4); elem at blk*512 + lane*8 + (k&7),
// lane = ((k>>3)&1)*32 + (n&31). A wave B-fragment load = one coalesced 1KB.
// ---------------------------------------------------------------------------
__global__ __launch_bounds__(256) void prep_all(const float* __restrict__ Wq,
                                                const float* __restrict__ Wk,
                                                const float* __restrict__ Wv,
                                                const float* __restrict__ Wo,
                                                const float* __restrict__ W1,
                                                const float* __restrict__ W2,
                                                __bf16* __restrict__ BtQKV,
                                                __bf16* __restrict__ BtO,
                                                __bf16* __restrict__ Bt1,
                                                __bf16* __restrict__ Bt2,
                                                const float* __restrict__ emb,
                                                const float* __restrict__ g1,
                                                const float* __restrict__ be1,
                                                __bf16* __restrict__ h) {
    int id = blockIdx.x;
    int tid = threadIdx.x;
    if (id >= 12288) {
        // ---- LayerNorm1 row ----
        int row = id - 12288;
        size_t i = (size_t)row * HIDDEN + tid * 4;
        float4 v = *(const float4*)(emb + i);
        float s  = v.x + v.y + v.z + v.w;
        float s2 = v.x * v.x + v.y * v.y + v.z * v.z + v.w * v.w;
#pragma unroll
        for (int off = 1; off < 64; off <<= 1) {
            s  += __shfl_xor(s, off, 64);
            s2 += __shfl_xor(s2, off, 64);
        }
        __shared__ float red[8];
        int wid = tid >> 6;
        if ((tid & 63) == 0) { red[wid] = s; red[wid + 4] = s2; }
        __syncthreads();
        s  = red[0] + red[1] + red[2] + red[3];
        s2 = red[4] + red[5] + red[6] + red[7];
        float mu  = s * (1.0f / HIDDEN);
        float var = fmaxf(s2 * (1.0f / HIDDEN) - mu * mu, 0.0f);
        float inv = rsqrtf(var + 1e-5f);
        float4 gv = *(const float4*)(g1 + tid * 4);
        float4 bv = *(const float4*)(be1 + tid * 4);
        bf16x4 o;
        o[0] = (__bf16)((v.x - mu) * inv * gv.x + bv.x);
        o[1] = (__bf16)((v.y - mu) * inv * gv.y + bv.y);
        o[2] = (__bf16)((v.z - mu) * inv * gv.z + bv.z);
        o[3] = (__bf16)((v.w - mu) * inv * gv.w + bv.w);
        *(bf16x4*)(h + i) = o;
        return;
    }
    // ---- weight convert tile (32x32) ----
    __shared__ float t[32][33];
    const float* in; __bf16* out; int K, N, nt, kt;
    if (id < 4096) {
        int job = id >> 10, tt = id & 1023;
        nt = tt & 31; kt = tt >> 5; K = 1024; N = 1024;
        if (job == 0)      { in = Wq; out = BtQKV; }
        else if (job == 1) { in = Wk; out = BtQKV + 1024 * 1024; }
        else if (job == 2) { in = Wv; out = BtQKV + 2 * 1024 * 1024; }
        else               { in = Wo; out = BtO; }
    } else if (id < 8192) {
        int tt = id - 4096;
        nt = tt & 127; kt = tt >> 7; K = 1024; N = 4096; in = W1; out = Bt1;
    } else {
        int tt = id - 8192;
        nt = tt & 31; kt = tt >> 5; K = 4096; N = 1024; in = W2; out = Bt2;
    }
    int n0 = nt * 32, k0 = kt * 32;
    int r  = tid >> 3;             // n within tile
    int c4 = (tid & 7) * 4;        // k run of 4
    float4 v = *(const float4*)(in + (size_t)(k0 + r) * N + n0 + c4);
    t[r][c4 + 0] = v.x; t[r][c4 + 1] = v.y; t[r][c4 + 2] = v.z; t[r][c4 + 3] = v.w;
    __syncthreads();
    bf16x4 o;
    o[0] = (__bf16)t[c4 + 0][r];
    o[1] = (__bf16)t[c4 + 1][r];
    o[2] = (__bf16)t[c4 + 2][r];
    o[3] = (__bf16)t[c4 + 3][r];
    int n = n0 + r, k = k0 + c4;
    size_t blk = (size_t)(n >> 5) * (K >> 4) + (k >> 4);
    int ln = ((k >> 3) & 1) * 32 + (n & 31);
    *(bf16x4*)(out + blk * 512 + ln * 8 + (k & 7)) = o;
}

// ---------------------------------------------------------------------------
// Fused Wo-split-K reduction + residual + LayerNorm2.
// x1 = emb + p0 + p1 -> out (fp32); h2 = LN2(x1) (bf16).
// ---------------------------------------------------------------------------
__global__ __launch_bounds__(256) void red_wo_ln(const float* __restrict__ emb,
                                                 const __bf16* __restrict__ p0,
                                                 const __bf16* __restrict__ p1,
                                                 const float* __restrict__ g,
                                                 const float* __restrict__ beta,
                                                 float* __restrict__ out,
                                                 __bf16* __restrict__ h2) {
    int row = blockIdx.x;
    int tid = threadIdx.x;
    size_t i = (size_t)row * HIDDEN + tid * 4;
    float4 e = *(const float4*)(emb + i);
    bf16x4 a = *(const bf16x4*)(p0 + i);
    bf16x4 b = *(const bf16x4*)(p1 + i);
    float4 v;
    v.x = e.x + (float)a[0] + (float)b[0];
    v.y = e.y + (float)a[1] + (float)b[1];
    v.z = e.z + (float)a[2] + (float)b[2];
    v.w = e.w + (float)a[3] + (float)b[3];
    *(float4*)(out + i) = v;

    float s  = v.x + v.y + v.z + v.w;
    float s2 = v.x * v.x + v.y * v.y + v.z * v.z + v.w * v.w;
#pragma unroll
    for (int off = 1; off < 64; off <<= 1) {
        s  += __shfl_xor(s, off, 64);
        s2 += __shfl_xor(s2, off, 64);
    }
    __shared__ float red[8];
    int wid = tid >> 6;
    if ((tid & 63) == 0) { red[wid] = s; red[wid + 4] = s2; }
    __syncthreads();
    s  = red[0] + red[1] + red[2] + red[3];
    s2 = red[4] + red[5] + red[6] + red[7];
    float mu  = s * (1.0f / HIDDEN);
    float var = fmaxf(s2 * (1.0f / HIDDEN) - mu * mu, 0.0f);
    float inv = rsqrtf(var + 1e-5f);
    float4 gv = *(const float4*)(g + tid * 4);
    float4 bv = *(const float4*)(beta + tid * 4);
    bf16x4 o;
    o[0] = (__bf16)((v.x - mu) * inv * gv.x + bv.x);
    o[1] = (__bf16)((v.y - mu) * inv * gv.y + bv.y);
    o[2] = (__bf16)((v.z - mu) * inv * gv.z + bv.z);
    o[3] = (__bf16)((v.w - mu) * inv * gv.w + bv.w);
    *(bf16x4*)(h2 + i) = o;
}

// ---------------------------------------------------------------------------
// W2 reduction: out += p0+p1+p2+p3 + b2[col]  (in-place on out)
// ---------------------------------------------------------------------------
__global__ __launch_bounds__(256) void red_w2(const __bf16* __restrict__ p0,
                                              const __bf16* __restrict__ p3,
                                              const float* __restrict__ b2,
                                              float* __restrict__ out,
                                              int N) {
    size_t i = ((size_t)blockIdx.x * 256 + threadIdx.x) * 8;
    const size_t MN = (size_t)ROWS * HIDDEN;
    bf16x8 a = *(const bf16x8*)(p0 + i);
    bf16x8 b = *(const bf16x8*)(p0 + MN + i);
    bf16x8 c = *(const bf16x8*)(p0 + 2 * MN + i);
    bf16x8 d = *(const bf16x8*)(p3 + i);
    int col = (int)(i & (size_t)(N - 1));
    float4 bb0 = *(const float4*)(b2 + col);
    float4 bb1 = *(const float4*)(b2 + col + 4);
    float4 o0 = *(const float4*)(out + i);
    float4 o1 = *(const float4*)(out + i + 4);
    o0.x += (float)a[0] + (float)b[0] + (float)c[0] + (float)d[0] + bb0.x;
    o0.y += (float)a[1] + (float)b[1] + (float)c[1] + (float)d[1] + bb0.y;
    o0.z += (float)a[2] + (float)b[2] + (float)c[2] + (float)d[2] + bb0.z;
    o0.w += (float)a[3] + (float)b[3] + (float)c[3] + (float)d[3] + bb0.w;
    o1.x += (float)a[4] + (float)b[4] + (float)c[4] + (float)d[4] + bb1.x;
    o1.y += (float)a[5] + (float)b[5] + (float)c[5] + (float)d[5] + bb1.y;
    o1.z += (float)a[6] + (float)b[6] + (float)c[6] + (float)d[6] + bb1.z;
    o1.w += (float)a[7] + (float)b[7] + (float)c[7] + (float)d[7] + bb1.w;
    *(float4*)(out + i)     = o0;
    *(float4*)(out + i + 4) = o1;
}

// ---------------------------------------------------------------------------
// Shared MFMA core, 32x32x16. A via LDS (XOR-swizzled, double-buffered
// global_load_lds); B DIRECT global->VGPR from fragment-major BtF with
// one-iteration register prefetch.
// ---------------------------------------------------------------------------
__device__ __forceinline__ void mfma_core128(const __bf16* __restrict__ A,
                                             const __bf16* __restrict__ BtF,
                                             int Kstride, int kbase, int Klen,
                                             int m0, int n0, int tid,
                                             floatx16 (&acc)[2][2]) {
    __shared__ __bf16 As[2 * 128 * 32];
    const int BUF = 128 * 32;
    int lane = tid & 63;
    int wave = tid >> 6;
    int wr = wave >> 1, wc = wave & 1;

    int sr = lane >> 2;                                // row within 16
    int sk = 8 * ((lane & 3) ^ ((sr >> 1) & 3));       // swizzled global chunk
    const __bf16* ga0 = A + (size_t)(m0 + wave * 16 + sr) * Kstride + kbase + sk;
    const __bf16* ga1 = ga0 + (size_t)64 * Kstride;
    __bf16* la0 = &As[wave * 512];
    __bf16* la1 = &As[2048 + wave * 512];

    int fm = lane & 31;
    int gswz = (lane >> 1) & 3;
    int slot0 = ((lane >> 5) + 0) ^ gswz;
    int slot1 = ((lane >> 5) + 2) ^ gswz;

    const __bf16* bb = BtF + ((size_t)((n0 >> 5) + wc * 2) * (Kstride >> 4)) * 512
                     + (size_t)lane * 8;
    const size_t jstr = (size_t)(Kstride >> 4) * 512;
    int ci0 = kbase >> 4;

    __builtin_amdgcn_global_load_lds(AS1(ga0), AS3(la0), 16, 0, 0);
    __builtin_amdgcn_global_load_lds(AS1(ga1), AS3(la1), 16, 0, 0);
    bf16x8 bcur[2][2], bnxt[2][2];
#pragma unroll
    for (int j = 0; j < 2; j++)
#pragma unroll
        for (int t = 0; t < 2; t++)
            bcur[j][t] = *(const bf16x8*)(bb + j * jstr + (size_t)(ci0 + t) * 512);

    int buf = 0;
    for (int k0 = 0; k0 < Klen; k0 += 32, buf ^= 1) {
        __syncthreads();
        if (k0 + 32 < Klen) {
            int nb = (buf ^ 1) * BUF;
            __builtin_amdgcn_global_load_lds(AS1(ga0 + k0 + 32), AS3(la0 + nb), 16, 0, 0);
            __builtin_amdgcn_global_load_lds(AS1(ga1 + k0 + 32), AS3(la1 + nb), 16, 0, 0);
            int ci = ci0 + ((k0 + 32) >> 4);
#pragma unroll
            for (int j = 0; j < 2; j++)
#pragma unroll
                for (int t = 0; t < 2; t++)
                    bnxt[j][t] = *(const bf16x8*)(bb + j * jstr + (size_t)(ci + t) * 512);
        }
        const __bf16* Ab = As + buf * BUF;
        bf16x8 af[2][2];
#pragma unroll
        for (int i = 0; i < 2; i++) {
            const __bf16* rp = Ab + (size_t)(wr * 64 + i * 32 + fm) * 32;
            af[i][0] = *(const bf16x8*)(rp + slot0 * 8);
            af[i][1] = *(const bf16x8*)(rp + slot1 * 8);
        }
#pragma unroll
        for (int t = 0; t < 2; t++)
#pragma unroll
            for (int i = 0; i < 2; i++)
#pragma unroll
                for (int j = 0; j < 2; j++)
                    acc[i][j] = __builtin_amdgcn_mfma_f32_32x32x16_bf16(
                        af[i][t], bcur[j][t], acc[i][j], 0, 0, 0);
#pragma unroll
        for (int j = 0; j < 2; j++)
#pragma unroll
            for (int t = 0; t < 2; t++)
                bcur[j][t] = bnxt[j][t];
    }
}

// ---------------------------------------------------------------------------
// Full-K GEMM with epilogue (W1). Grid: x = M-tiles, y = N-tiles.
// ---------------------------------------------------------------------------
template <typename OutT, bool BIAS, bool RELU>
__global__ __launch_bounds__(256) void mgemm(const __bf16* __restrict__ A,
                                             const __bf16* __restrict__ BtF,
                                             const float* __restrict__ bias,
                                             OutT* __restrict__ C,
                                             int N, int Kstride, int Klen) {
    int tid = threadIdx.x;
    int lane = tid & 63;
    int wave = tid >> 6;
    int m0 = blockIdx.x * 128, n0 = blockIdx.y * 128;
    int wr = wave >> 1, wc = wave & 1;
    floatx16 acc[2][2] = {};
    mfma_core128(A, BtF, Kstride, 0, Klen, m0, n0, tid, acc);

#pragma unroll
    for (int i = 0; i < 2; i++) {
#pragma unroll
        for (int j = 0; j < 2; j++) {
            int col  = n0 + wc * 64 + j * 32 + (lane & 31);
            int rowb = m0 + wr * 64 + i * 32 + 4 * (lane >> 5);
#pragma unroll
            for (int reg = 0; reg < 16; reg++) {
                int row = rowb + (reg & 3) + 8 * (reg >> 2);
                float v = acc[i][j][reg];
                if (BIAS) v += bias[col];
                if (RELU) v = fmaxf(v, 0.0f);
                C[(size_t)row * N + col] = (OutT)v;
            }
        }
    }
}

// ---------------------------------------------------------------------------
// QKV GEMM: q,k parts to qkv[4096][3072]; v-part written only as transposed
// Vt[bh][d][T] (vtrans-free).
// ---------------------------------------------------------------------------
__global__ __launch_bounds__(256) void mgemm_qkv(const __bf16* __restrict__ A,
                                                 const __bf16* __restrict__ BtF,
                                                 __bf16* __restrict__ C,
                                                 __bf16* __restrict__ Vt) {
    const int N = 3072;
    int tid = threadIdx.x;
    int lane = tid & 63;
    int wave = tid >> 6;
    int m0 = blockIdx.x * 128, n0 = blockIdx.y * 128;
    int wr = wave >> 1, wc = wave & 1;
    floatx16 acc[2][2] = {};
    mfma_core128(A, BtF, 1024, 0, 1024, m0, n0, tid, acc);

#pragma unroll
    for (int i = 0; i < 2; i++) {
#pragma unroll
        for (int j = 0; j < 2; j++) {
            int col  = n0 + wc * 64 + j * 32 + (lane & 31);
            int rowb = m0 + wr * 64 + i * 32 + 4 * (lane >> 5);
            if (col < 2048) {
#pragma unroll
                for (int reg = 0; reg < 16; reg++) {
                    int row = rowb + (reg & 3) + 8 * (reg >> 2);
                    C[(size_t)row * N + col] = (__bf16)acc[i][j][reg];
                }
            } else {
                int vcol = col - 2048;
                int hh = vcol >> 6, dd = vcol & 63;
#pragma unroll
                for (int rq = 0; rq < 4; rq++) {
                    int row0 = rowb + 8 * rq;
                    int bb = row0 >> 11;
                    int tt = row0 & 2047;
                    bf16x4 pack;
                    pack[0] = (__bf16)acc[i][j][4 * rq + 0];
                    pack[1] = (__bf16)acc[i][j][4 * rq + 1];
                    pack[2] = (__bf16)acc[i][j][4 * rq + 2];
                    pack[3] = (__bf16)acc[i][j][4 * rq + 3];
                    *(bf16x4*)&Vt[(((size_t)bb * 16 + hh) * 64 + dd) * SEQ + tt] = pack;
                }
            }
        }
    }
}

// ---------------------------------------------------------------------------
// Split-K GEMM: blockIdx.z picks K-chunk; writes bf16 partial tile.
// z<3 at P0 + z*M*N; z==3 at P3.
// ---------------------------------------------------------------------------
__global__ __launch_bounds__(256) void mgemm_sk(const __bf16* __restrict__ A,
                                                const __bf16* __restrict__ BtF,
                                                __bf16* __restrict__ P0,
                                                __bf16* __restrict__ P3,
                                                int M, int N, int Kstride, int Klen) {
    int z = blockIdx.z;
    __bf16* C = (z == 3) ? P3 : (P0 + (size_t)z * M * N);
    int tid = threadIdx.x;
    int lane = tid & 63;
    int wave = tid >> 6;
    int m0 = blockIdx.x * 128, n0 = blockIdx.y * 128;
    int wr = wave >> 1, wc = wave & 1;
    floatx16 acc[2][2] = {};
    mfma_core128(A, BtF, Kstride, z * Klen, Klen, m0, n0, tid, acc);

#pragma unroll
    for (int i = 0; i < 2; i++) {
#pragma unroll
        for (int j = 0; j < 2; j++) {
            int col  = n0 + wc * 64 + j * 32 + (lane & 31);
            int rowb = m0 + wr * 64 + i * 32 + 4 * (lane >> 5);
#pragma unroll
            for (int reg = 0; reg < 16; reg++) {
                int row = rowb + (reg & 3) + 8 * (reg >> 2);
                C[(size_t)row * N + col] = (__bf16)acc[i][j][reg];
            }
        }
    }
}

// ---------------------------------------------------------------------------
// MFMA flash attention (verified R8): no-max softmax, exp2, ones-MFMA l,
// K/V register prefetch.
// ---------------------------------------------------------------------------
__global__ __launch_bounds__(256) void attn_mfma(const __bf16* __restrict__ qkv,
                                                 const __bf16* __restrict__ Vt,
                                                 __bf16* __restrict__ ctx) {
    __shared__ __bf16 Ks[64 * 64];
    __shared__ __bf16 Vs[64 * 64];
    __shared__ __bf16 Ps[4][16 * 64];
    const int QKVW = 3 * HIDDEN;

    int bh = blockIdx.x;
    int qt = gridDim.y - 1 - blockIdx.y;
    int b = bh >> 4, h = bh & 15;
    int tid = threadIdx.x;
    int lane = tid & 63;
    int w = tid >> 6;
    int m = lane & 15;
    int g = lane >> 4;

    const float QSC = 1.44269504f / 8.0f;
    bf16x8 qf[2];
    {
        const __bf16* Qp = qkv + (size_t)(b * SEQ + qt * 64 + w * 16 + m) * QKVW
                         + h * HDIM + g * 8;
        qf[0] = *(const bf16x8*)(Qp);
        qf[1] = *(const bf16x8*)(Qp + 32);
#pragma unroll
        for (int t = 0; t < 2; t++)
#pragma unroll
            for (int i = 0; i < 8; i++)
                qf[t][i] = (__bf16)((float)qf[t][i] * QSC);
    }

    bf16x8 onesf;
#pragma unroll
    for (int i = 0; i < 8; i++) onesf[i] = (__bf16)1.0f;

    floatx4 oacc[4] = {};
    floatx4 lacc = {};

    int srow = tid >> 2;
    int sc0  = (tid & 3) * 2;
    const __bf16* Kg = qkv + (size_t)(b * SEQ) * QKVW + HIDDEN + h * HDIM;
    const __bf16* Vg = Vt + (size_t)bh * HDIM * SEQ;

    bf16x8 pk0, pk1, pv0, pv1;
    {
        const __bf16* kp = Kg + (size_t)srow * QKVW + sc0 * 8;
        pk0 = *(const bf16x8*)kp;
        pk1 = *(const bf16x8*)(kp + 8);
        const __bf16* vp = Vg + (size_t)srow * SEQ + sc0 * 8;
        pv0 = *(const bf16x8*)vp;
        pv1 = *(const bf16x8*)(vp + 8);
    }

    for (int kt = 0; kt <= qt; kt++) {
        __syncthreads();
        *(bf16x8*)&Ks[srow * 64 + SWZ(srow, sc0)]     = pk0;
        *(bf16x8*)&Ks[srow * 64 + SWZ(srow, sc0 + 1)] = pk1;
        *(bf16x8*)&Vs[srow * 64 + SWZ(srow, sc0)]     = pv0;
        *(bf16x8*)&Vs[srow * 64 + SWZ(srow, sc0 + 1)] = pv1;
        __syncthreads();

        if (kt < qt) {
            const __bf16* kp = Kg + (size_t)((kt + 1) * 64 + srow) * QKVW + sc0 * 8;
            pk0 = *(const bf16x8*)kp;
            pk1 = *(const bf16x8*)(kp + 8);
            const __bf16* vp = Vg + (size_t)srow * SEQ + (kt + 1) * 64 + sc0 * 8;
            pv0 = *(const bf16x8*)vp;
            pv1 = *(const bf16x8*)(vp + 8);
        }

        floatx4 sacc[4] = {};
#pragma unroll
        for (int j = 0; j < 4; j++) {
#pragma unroll
            for (int t = 0; t < 2; t++) {
                int kr = 16 * j + m;
                bf16x8 kf = *(const bf16x8*)&Ks[kr * 64 + SWZ(kr, g + 4 * t)];
                sacc[j] = __builtin_amdgcn_mfma_f32_16x16x32_bf16(
                    qf[t], kf, sacc[j], 0, 0, 0);
            }
        }

        if (kt == qt) {
            int qlocal = w * 16 + 4 * g;
#pragma unroll
            for (int j = 0; j < 4; j++)
#pragma unroll
                for (int r = 0; r < 4; r++)
                    if (16 * j + m > qlocal + r) sacc[j][r] = -INFINITY;
        }

        __bf16* Pw = &Ps[w][0];
#pragma unroll
        for (int j = 0; j < 4; j++)
#pragma unroll
            for (int r = 0; r < 4; r++) {
                float p = exp2f(sacc[j][r]);
                int row = 4 * g + r;
                int key = 16 * j + m;
                Pw[row * 64 + SWZ(row, key >> 3) + (key & 7)] = (__bf16)p;
            }

#pragma unroll
        for (int t = 0; t < 2; t++) {
            bf16x8 pf = *(const bf16x8*)&Pw[m * 64 + SWZ(m, g + 4 * t)];
            lacc = __builtin_amdgcn_mfma_f32_16x16x32_bf16(pf, onesf, lacc, 0, 0, 0);
#pragma unroll
            for (int jd = 0; jd < 4; jd++) {
                int vr = 16 * jd + m;
                bf16x8 vf = *(const bf16x8*)&Vs[vr * 64 + SWZ(vr, g + 4 * t)];
                oacc[jd] = __builtin_amdgcn_mfma_f32_16x16x32_bf16(
                    pf, vf, oacc[jd], 0, 0, 0);
            }
        }
    }

#pragma unroll
    for (int r = 0; r < 4; r++) {
        float invl = 1.0f / lacc[r];
        int row = qt * 64 + w * 16 + 4 * g + r;
        __bf16* cp = ctx + (size_t)(b * SEQ + row) * HIDDEN + h * HDIM;
#pragma unroll
        for (int jd = 0; jd < 4; jd++)
            cp[16 * jd + m] = (__bf16)(oacc[jd][r] * invl);
    }
}

// ---------------------------------------------------------------------------
extern "C" void kernel_launch(void* const* d_in, const int* in_sizes, int n_in,
                              void* d_out, int out_size, void* d_ws, size_t ws_size,
                              hipStream_t stream) {
    (void)in_sizes; (void)n_in; (void)out_size; (void)ws_size;
    const float* emb = (const float*)d_in[0];
    const float* Wq  = (const float*)d_in[1];
    const float* Wk  = (const float*)d_in[2];
    const float* Wv  = (const float*)d_in[3];
    const float* Wo  = (const float*)d_in[4];
    const float* W1  = (const float*)d_in[5];
    const float* b1  = (const float*)d_in[6];
    const float* W2  = (const float*)d_in[7];
    const float* b2  = (const float*)d_in[8];
    const float* g1  = (const float*)d_in[9];
    const float* be1 = (const float*)d_in[10];
    const float* g2  = (const float*)d_in[11];
    const float* be2 = (const float*)d_in[12];
    float* out = (float*)d_out;

    // ws layout (bf16 elems; ME = 1M elems = 2MB). Total 36 ME = 72 MB.
    //   [0,4)   h (LN1) -> ctx (attn out) -> ff1 head
    //   [4,16)  qkv (q,k cols used) -> Wo partials [4,12) -> ff1
    //   [16,20) h2 -> W2 partial z0
    //   [20,24) BtQKV+BtO -> W2 partial z1
    //   [24,28) Bt1 -> W2 partial z2
    //   [28,32) Bt2 (alive through W2 gemm)
    //   [32,36) Vt -> W2 partial z3
    __bf16* wsb = (__bf16*)d_ws;
    const size_t ME = 1024 * 1024;
    __bf16* h     = wsb;
    __bf16* qkv   = wsb + 4 * ME;
    __bf16* ctx   = wsb;
    __bf16* ff1   = wsb;
    __bf16* h2    = wsb + 16 * ME;
    __bf16* BtQKV = wsb + 20 * ME;
    __bf16* BtO   = wsb + 23 * ME;
    __bf16* Bt1   = wsb + 24 * ME;
    __bf16* Bt2   = wsb + 28 * ME;
    __bf16* Vt    = wsb + 32 * ME;
    __bf16* woP   = wsb + 4 * ME;    // 2 x 4 ME
    __bf16* w2P0  = wsb + 16 * ME;   // z0..z2 contiguous (12 ME)
    __bf16* w2P3  = wsb + 32 * ME;   // z3

    prep_all<<<16384, 256, 0, stream>>>(Wq, Wk, Wv, Wo, W1, W2,
                                        BtQKV, BtO, Bt1, Bt2,
                                        emb, g1, be1, h);

    mgemm_qkv<<<dim3(32, 24), 256, 0, stream>>>(h, BtQKV, qkv, Vt);

    attn_mfma<<<dim3(32, 32), 256, 0, stream>>>(qkv, Vt, ctx);

    // Wo split-K x2, bf16 partials
    mgemm_sk<<<dim3(32, 8, 2), 256, 0, stream>>>(
        ctx, BtO, woP, nullptr, ROWS, 1024, 1024, 512);
    red_wo_ln<<<ROWS, 256, 0, stream>>>(emb, woP, woP + 4 * ME, g2, be2, out, h2);

    mgemm<__bf16, true, true><<<dim3(32, 32), 256, 0, stream>>>(
        h2, Bt1, b1, ff1, 4096, 1024, 1024);

    // W2 split-K x4, bf16 partials
    mgemm_sk<<<dim3(32, 8, 4), 256, 0, stream>>>(
        ff1, Bt2, w2P0, w2P3, ROWS, 1024, 4096, 1024);
    red_w2<<<2048, 256, 0, stream>>>(w2P0, w2P3, b2, out, 1024);
}